// Round 1
// baseline (28557.721 us; speedup 1.0000x reference)
//
#include <hip/hip_runtime.h>

// ============================================================================
// 2-layer LSTM (H=1024, B=128, T=256, future=64), one persistent cooperative
// kernel. 256 WGs x 512 threads, 1 WG/CU. Each CU owns 4 h-units per layer
// (16 gate columns per matmul), weights live in LDS (packed in MFMA B-frag
// order) for the entire 320-step recurrence. One grid barrier per step
// (counter-based, 8 contention-split slots); AR steps add a mini-phase so
// out(t) can feed x(t+1). Precision: W fp16, h1 fp16, h2 split hi+lo fp16;
// all elementwise state fp32 in registers.
// ============================================================================

typedef _Float16 f16;
typedef _Float16 f16x8 __attribute__((ext_vector_type(8)));
typedef float    f32x4 __attribute__((ext_vector_type(4)));

#define NB   256
#define WGS  512
#define HS   1024
#define BS   128
#define TS   256
#define TTS  320
#define KST  32     // 1024 / 32

// workspace byte offsets
#define OFF_H1    0u         // f16 [2][128][1024]   524288 B
#define OFF_H2H   524288u    // f16 [2][128][1024]
#define OFF_H2L   1048576u   // f16 [2][128][1024]
#define OFF_CNT   1572864u   // int [320][8 slots x 64-int stride] = 655360 B
#define OFF_CNT2  2228224u   // same, for AR mini-phase
// end 2883584

// LDS byte offsets
#define LDS_G1    131072     // float[128][16]
#define LDS_G2    139264     // float[128][16]
#define LDS_XF    147456     // float[128]
#define LDS_PRM   147968     // wih1[16], b1[16], b2[16], blin
#define LDS_TOTAL 148480

__device__ __forceinline__ float sigm(float x){ return 1.0f/(1.0f + __expf(-x)); }

__global__ void init_ws_kernel(char* ws){
  // zero H2h[1], and H2l[1]+cnt+cnt2 (contiguous)
  const size_t n1 = (1048576u - 786432u) / 16u;
  const size_t n2 = (2883584u - 1310720u) / 16u;
  float4* r1 = (float4*)(ws + 786432u);
  float4* r2 = (float4*)(ws + 1310720u);
  float4 z = make_float4(0.f, 0.f, 0.f, 0.f);
  size_t stride = (size_t)gridDim.x * blockDim.x;
  for (size_t i = blockIdx.x*(size_t)blockDim.x + threadIdx.x; i < n1; i += stride) r1[i] = z;
  for (size_t i = blockIdx.x*(size_t)blockDim.x + threadIdx.x; i < n2; i += stride) r2[i] = z;
}

__global__ void __launch_bounds__(WGS, 2)
lstm_coop(const float* __restrict__ xg,
          const float* __restrict__ Wih1, const float* __restrict__ Whh1,
          const float* __restrict__ bih1, const float* __restrict__ bhh1,
          const float* __restrict__ Wih2, const float* __restrict__ Whh2,
          const float* __restrict__ bih2, const float* __restrict__ bhh2,
          const float* __restrict__ Wlin, const float* __restrict__ blin,
          float* __restrict__ outp, char* __restrict__ ws)
{
  extern __shared__ char smem[];
  f16*   Wlds = (f16*)smem;                    // [(tile*32+k0)*64+lane]*8 f16
  float* g1s  = (float*)(smem + LDS_G1);
  float* g2s  = (float*)(smem + LDS_G2);
  float* xfd  = (float*)(smem + LDS_XF);
  float* prm  = (float*)(smem + LDS_PRM);

  f16* H1  = (f16*)(ws + OFF_H1);
  f16* H2h = (f16*)(ws + OFF_H2H);
  f16* H2l = (f16*)(ws + OFF_H2L);
  int* cnt  = (int*)(ws + OFF_CNT);
  int* cnt2 = (int*)(ws + OFF_CNT2);

  const int tid = threadIdx.x;
  const int blk = blockIdx.x;

  // ---- prologue: pack weights into LDS in MFMA B-fragment order ----
  // tiles: 0=G1(Whh1) 1=G2a(Wih2) 2=G2b(Whh2) 3=OUT(Wlin col0, rest 0)
  // col n (=lane&15) -> W row (n>>2)*1024 + blk*4 + (n&3)   (n = gate*4 + unit)
  for (int item = tid; item < 4*KST*64; item += WGS) {
    int tile = item >> 11;
    int rem  = item & 2047;
    int k0   = rem >> 6;
    int lane = rem & 63;
    int n    = lane & 15;
    int kbase = k0*32 + (lane>>4)*8;
    f16x8 pk;
    if (tile < 3) {
      const float* Wsrc = (tile==0) ? Whh1 : (tile==1) ? Wih2 : Whh2;
      const float* p = Wsrc + (size_t)((n>>2)*1024 + blk*4 + (n&3))*HS + kbase;
      #pragma unroll
      for (int j=0;j<8;j++) pk[j] = (f16)p[j];
    } else {
      #pragma unroll
      for (int j=0;j<8;j++) pk[j] = (n==0) ? (f16)Wlin[kbase+j] : (f16)0.0f;
    }
    *(f16x8*)(Wlds + (size_t)item*8) = pk;
  }
  if (tid < 16) {
    int row = (tid>>2)*1024 + blk*4 + (tid&3);
    prm[tid]      = Wih1[row];
    prm[16 + tid] = bih1[row] + bhh1[row];
    prm[32 + tid] = bih2[row] + bhh2[row];
  }
  if (tid == 16) prm[48] = blin[0];
  __syncthreads();

  // elementwise identity: thread -> (batch row, unit-within-CU)
  const int erow = tid >> 2;
  const int eu   = tid & 3;
  float c1 = 0.f, c2 = 0.f;

  // ---- E1(0): h1(0) from x(0) only (h1(-1)=0, c1(-1)=0) ----
  {
    float xv = xg[erow*TS + 0];
    float gi = xv*prm[0*4+eu] + prm[16 + 0*4+eu];
    float gg = xv*prm[2*4+eu] + prm[16 + 2*4+eu];
    float go = xv*prm[3*4+eu] + prm[16 + 3*4+eu];
    c1 = sigm(gi)*tanhf(gg);
    float h1v = sigm(go)*tanhf(c1);
    H1[(size_t)0*BS*HS + erow*HS + blk*4 + eu] = (f16)h1v;
  }
  __syncthreads();
  if (tid == 0) {
    __threadfence();
    __hip_atomic_fetch_add(&cnt[0*512 + (blk&7)*64], 1, __ATOMIC_RELEASE, __HIP_MEMORY_SCOPE_AGENT);
  }

  // MFMA identity
  const int wv    = tid >> 6;
  const int lane  = tid & 63;
  const int n15   = lane & 15;
  const int mrow  = wv*16 + n15;          // A-frag row
  const int kc    = (lane>>4)*8;          // A/B-frag k sub-offset
  const int rbase = wv*16 + (lane>>4)*4;  // C/D row base
  const f16x8* WB = (const f16x8*)Wlds;

  for (int t = 0; t < TTS; ++t) {
    // ---- wait for H1(t) and H2(t-1) ----
    while (__hip_atomic_load(&cnt[t*512 + (tid&7)*64], __ATOMIC_ACQUIRE, __HIP_MEMORY_SCOPE_AGENT) < 32)
      __builtin_amdgcn_s_sleep(2);
    __syncthreads();

    const f16* A1  = H1  + (size_t)(t&1)*BS*HS     + mrow*HS + kc;
    const f16* A2h = H2h + (size_t)((t+1)&1)*BS*HS + mrow*HS + kc;  // parity(t-1)
    const f16* A2l = H2l + (size_t)((t+1)&1)*BS*HS + mrow*HS + kc;

    f32x4 acc1  = {0.f,0.f,0.f,0.f};
    f32x4 acc2a = {0.f,0.f,0.f,0.f};
    f32x4 acc2b = {0.f,0.f,0.f,0.f};
    f32x4 accO  = {0.f,0.f,0.f,0.f};
    #pragma unroll 4
    for (int k0 = 0; k0 < KST; ++k0) {
      f16x8 a1  = *(const f16x8*)(A1  + k0*32);
      f16x8 a2h = *(const f16x8*)(A2h + k0*32);
      f16x8 a2l = *(const f16x8*)(A2l + k0*32);
      f16x8 b0 = WB[(0*KST + k0)*64 + lane];
      f16x8 b1 = WB[(1*KST + k0)*64 + lane];
      f16x8 b2 = WB[(2*KST + k0)*64 + lane];
      f16x8 b3 = WB[(3*KST + k0)*64 + lane];
      acc1  = __builtin_amdgcn_mfma_f32_16x16x32_f16(a1,  b0, acc1,  0,0,0);
      acc2a = __builtin_amdgcn_mfma_f32_16x16x32_f16(a1,  b1, acc2a, 0,0,0);
      acc2b = __builtin_amdgcn_mfma_f32_16x16x32_f16(a2h, b2, acc2b, 0,0,0);
      acc2b = __builtin_amdgcn_mfma_f32_16x16x32_f16(a2l, b2, acc2b, 0,0,0);
      accO  = __builtin_amdgcn_mfma_f32_16x16x32_f16(a2h, b3, accO,  0,0,0);
      accO  = __builtin_amdgcn_mfma_f32_16x16x32_f16(a2l, b3, accO,  0,0,0);
    }
    // ---- stage gates to LDS; store out(t-1) (teacher-forced range) ----
    #pragma unroll
    for (int r = 0; r < 4; ++r) {
      int grow = rbase + r;
      g2s[grow*16 + n15] = acc2a[r] + acc2b[r] + prm[32 + n15];
      g1s[grow*16 + n15] = acc1[r]  + prm[16 + n15];
    }
    if (n15 == 0 && blk == 0 && t >= 1 && t <= TS-1) {
      #pragma unroll
      for (int r = 0; r < 4; ++r) outp[(rbase+r)*TTS + (t-1)] = accO[r] + prm[48];
    }
    __syncthreads();

    // ---- E2(t): c2,h2 update; write h2 hi+lo ----
    {
      float gi = g2s[erow*16 + 0*4+eu];
      float gf = g2s[erow*16 + 1*4+eu];
      float gg = g2s[erow*16 + 2*4+eu];
      float go = g2s[erow*16 + 3*4+eu];
      c2 = sigm(gf)*c2 + sigm(gi)*tanhf(gg);
      float h2v = sigm(go)*tanhf(c2);
      f16 hh = (f16)h2v;
      float lo = h2v - (float)hh;
      size_t idx = (size_t)(t&1)*BS*HS + erow*HS + blk*4 + eu;
      H2h[idx] = hh;
      H2l[idx] = (f16)lo;
    }

    // ---- AR mini-phase: out(t) = h2(t)·Wlin, computed redundantly per CU ----
    if (t >= TS-1) {
      __syncthreads();
      if (tid == 0) {
        __threadfence();
        __hip_atomic_fetch_add(&cnt2[t*512 + (blk&7)*64], 1, __ATOMIC_RELEASE, __HIP_MEMORY_SCOPE_AGENT);
      }
      while (__hip_atomic_load(&cnt2[t*512 + (tid&7)*64], __ATOMIC_ACQUIRE, __HIP_MEMORY_SCOPE_AGENT) < 32)
        __builtin_amdgcn_s_sleep(2);
      __syncthreads();
      const f16* C2h = H2h + (size_t)(t&1)*BS*HS + mrow*HS + kc;
      const f16* C2l = H2l + (size_t)(t&1)*BS*HS + mrow*HS + kc;
      f32x4 aco = {0.f,0.f,0.f,0.f};
      #pragma unroll 4
      for (int k0 = 0; k0 < KST; ++k0) {
        f16x8 ah = *(const f16x8*)(C2h + k0*32);
        f16x8 al = *(const f16x8*)(C2l + k0*32);
        f16x8 b3 = WB[(3*KST + k0)*64 + lane];
        aco = __builtin_amdgcn_mfma_f32_16x16x32_f16(ah, b3, aco, 0,0,0);
        aco = __builtin_amdgcn_mfma_f32_16x16x32_f16(al, b3, aco, 0,0,0);
      }
      if (n15 == 0) {
        #pragma unroll
        for (int r = 0; r < 4; ++r) {
          float o = aco[r] + prm[48];
          xfd[rbase + r] = o;
          if (blk == 0) outp[(rbase+r)*TTS + t] = o;
        }
      }
      __syncthreads();
    }

    // ---- E1(t+1): c1,h1 update; write h1; arrive cnt[t+1] ----
    if (t < TTS-1) {
      float xv = (t+1 < TS) ? xg[erow*TS + (t+1)] : xfd[erow];
      float gi = g1s[erow*16 + 0*4+eu] + xv*prm[0*4+eu];
      float gf = g1s[erow*16 + 1*4+eu] + xv*prm[1*4+eu];
      float gg = g1s[erow*16 + 2*4+eu] + xv*prm[2*4+eu];
      float go = g1s[erow*16 + 3*4+eu] + xv*prm[3*4+eu];
      c1 = sigm(gf)*c1 + sigm(gi)*tanhf(gg);
      float h1v = sigm(go)*tanhf(c1);
      H1[(size_t)((t+1)&1)*BS*HS + erow*HS + blk*4 + eu] = (f16)h1v;
      __syncthreads();
      if (tid == 0) {
        __threadfence();
        __hip_atomic_fetch_add(&cnt[(t+1)*512 + (blk&7)*64], 1, __ATOMIC_RELEASE, __HIP_MEMORY_SCOPE_AGENT);
      }
    }
  }
}

extern "C" void kernel_launch(void* const* d_in, const int* in_sizes, int n_in,
                              void* d_out, int out_size, void* d_ws, size_t ws_size,
                              hipStream_t stream) {
  const float* xg   = (const float*)d_in[0];
  const float* Wih1 = (const float*)d_in[1];
  const float* Whh1 = (const float*)d_in[2];
  const float* bih1 = (const float*)d_in[3];
  const float* bhh1 = (const float*)d_in[4];
  const float* Wih2 = (const float*)d_in[5];
  const float* Whh2 = (const float*)d_in[6];
  const float* bih2 = (const float*)d_in[7];
  const float* bhh2 = (const float*)d_in[8];
  const float* Wlin = (const float*)d_in[9];
  const float* blin = (const float*)d_in[10];
  float* outp = (float*)d_out;
  char* ws = (char*)d_ws;

  init_ws_kernel<<<dim3(128), dim3(256), 0, stream>>>(ws);

  (void)hipFuncSetAttribute((const void*)lstm_coop,
                            hipFuncAttributeMaxDynamicSharedMemorySize, LDS_TOTAL);

  void* args[] = { (void*)&xg, (void*)&Wih1, (void*)&Whh1, (void*)&bih1, (void*)&bhh1,
                   (void*)&Wih2, (void*)&Whh2, (void*)&bih2, (void*)&bhh2,
                   (void*)&Wlin, (void*)&blin, (void*)&outp, (void*)&ws };
  hipError_t err = hipLaunchCooperativeKernel((const void*)lstm_coop,
                                              dim3(NB), dim3(WGS), args, LDS_TOTAL, stream);
  if (err != hipSuccess) {
    // 256 WGs at 1 WG/CU fit a 256-CU device; plain launch is co-resident too.
    lstm_coop<<<dim3(NB), dim3(WGS), LDS_TOTAL, stream>>>(
        xg, Wih1, Whh1, bih1, bhh1, Wih2, Whh2, bih2, bhh2, Wlin, blin, outp, ws);
  }
}

// Round 2
// 14472.061 us; speedup vs baseline: 1.9733x; 1.9733x over previous
//
#include <hip/hip_runtime.h>

// ============================================================================
// 2-layer LSTM (H=1024, B=128, T=256, future=64), persistent cooperative
// kernel, 256 WGs x 512 thr, 1 WG/CU, weights in LDS (MFMA B-frag order).
// R2: sync redesign — relaxed polls (one buffer_inv per step, not per poll),
// write-through h stores (no wbl2 walk), 1-wave pollers, 8KB-spread counter
// slots, accO uses h2-hi only.
// ============================================================================

typedef _Float16 f16;
typedef _Float16 f16x8 __attribute__((ext_vector_type(8)));
typedef float    f32x4 __attribute__((ext_vector_type(4)));
typedef unsigned int   u32;
typedef unsigned short u16;

#define NB   256
#define WGS  512
#define HS   1024
#define BS   128
#define TS   256
#define TTS  320
#define KST  32     // 1024 / 32

// workspace byte offsets
#define OFF_H1    0u         // f16 [2][128][1024]  524288 B
#define OFF_H2H   524288u    // f16 [2][128][1024]
#define OFF_H2L   1048576u   // f16 [2][128][1024]
#define OFF_CNT   1572864u   // int [8 slots x 8KB stride][t]  = 65536 B
#define OFF_CNT2  1638400u   // same
// end 1703936

#define SLOT_STRIDE 2048     // ints: 8KB between slots

// LDS byte offsets
#define LDS_G1    131072     // float[128][16]
#define LDS_G2    139264     // float[128][16]
#define LDS_XF    147456     // float[128]
#define LDS_PRM   147968     // wih1[16], b1[16], b2[16], blin
#define LDS_TOTAL 148480

__device__ __forceinline__ float sigm(float x){ return 1.0f/(1.0f + __expf(-x)); }

__device__ __forceinline__ void wt_store(u32* p, u32 v) {
  __hip_atomic_store(p, v, __ATOMIC_RELAXED, __HIP_MEMORY_SCOPE_AGENT);
}

// pack (even,odd)-unit f16 values; even lanes store 4B write-through
__device__ __forceinline__ void store_pair_wt(f16* addr, int eu, u16 mine) {
  u16 oth = (u16)__shfl_xor((int)mine, 1);
  if ((eu & 1) == 0) {
    u32 pk = (u32)mine | ((u32)oth << 16);
    wt_store((u32*)addr, pk);
  }
}

// arrival: all write-through stores drained, then one relaxed add
__device__ __forceinline__ void bar_arrive(int* cnt, int t, int blk) {
  asm volatile("s_waitcnt vmcnt(0)" ::: "memory");
  __syncthreads();
  if (threadIdx.x == 0)
    __hip_atomic_fetch_add(cnt + (blk & 7) * SLOT_STRIDE + t, 1,
                           __ATOMIC_RELAXED, __HIP_MEMORY_SCOPE_AGENT);
}

// wait: lanes 0..7 of wave 0 poll the 8 slots relaxed; one acquire fence after
__device__ __forceinline__ void bar_wait(const int* cnt, int t) {
  if (threadIdx.x < 8) {
    const int* p = cnt + threadIdx.x * SLOT_STRIDE + t;
    while (__hip_atomic_load(p, __ATOMIC_RELAXED, __HIP_MEMORY_SCOPE_AGENT) < 32)
      __builtin_amdgcn_s_sleep(2);
  }
  __syncthreads();
  __builtin_amdgcn_fence(__ATOMIC_ACQUIRE, "agent");
}

__global__ void init_ws_kernel(char* ws){
  // zero H2h[1]  (786432..1048576) and H2l[1]+cnt+cnt2 (1310720..1703936)
  const size_t n1 = (1048576u - 786432u) / 16u;
  const size_t n2 = (1703936u - 1310720u) / 16u;
  float4* r1 = (float4*)(ws + 786432u);
  float4* r2 = (float4*)(ws + 1310720u);
  float4 z = make_float4(0.f, 0.f, 0.f, 0.f);
  size_t stride = (size_t)gridDim.x * blockDim.x;
  for (size_t i = blockIdx.x*(size_t)blockDim.x + threadIdx.x; i < n1; i += stride) r1[i] = z;
  for (size_t i = blockIdx.x*(size_t)blockDim.x + threadIdx.x; i < n2; i += stride) r2[i] = z;
}

__global__ void __launch_bounds__(WGS, 2)
lstm_coop(const float* __restrict__ xg,
          const float* __restrict__ Wih1, const float* __restrict__ Whh1,
          const float* __restrict__ bih1, const float* __restrict__ bhh1,
          const float* __restrict__ Wih2, const float* __restrict__ Whh2,
          const float* __restrict__ bih2, const float* __restrict__ bhh2,
          const float* __restrict__ Wlin, const float* __restrict__ blin,
          float* __restrict__ outp, char* __restrict__ ws)
{
  extern __shared__ char smem[];
  f16*   Wlds = (f16*)smem;                    // [(tile*32+k0)*64+lane]*8 f16
  float* g1s  = (float*)(smem + LDS_G1);
  float* g2s  = (float*)(smem + LDS_G2);
  float* xfd  = (float*)(smem + LDS_XF);
  float* prm  = (float*)(smem + LDS_PRM);

  f16* H1  = (f16*)(ws + OFF_H1);
  f16* H2h = (f16*)(ws + OFF_H2H);
  f16* H2l = (f16*)(ws + OFF_H2L);
  int* cnt  = (int*)(ws + OFF_CNT);
  int* cnt2 = (int*)(ws + OFF_CNT2);

  const int tid = threadIdx.x;
  const int blk = blockIdx.x;

  // ---- prologue: pack weights into LDS in MFMA B-fragment order ----
  // tiles: 0=G1(Whh1) 1=G2a(Wih2) 2=G2b(Whh2) 3=OUT(Wlin col0, rest 0)
  for (int item = tid; item < 4*KST*64; item += WGS) {
    int tile = item >> 11;
    int rem  = item & 2047;
    int k0   = rem >> 6;
    int lane = rem & 63;
    int n    = lane & 15;
    int kbase = k0*32 + (lane>>4)*8;
    f16x8 pk;
    if (tile < 3) {
      const float* Wsrc = (tile==0) ? Whh1 : (tile==1) ? Wih2 : Whh2;
      const float* p = Wsrc + (size_t)((n>>2)*1024 + blk*4 + (n&3))*HS + kbase;
      #pragma unroll
      for (int j=0;j<8;j++) pk[j] = (f16)p[j];
    } else {
      #pragma unroll
      for (int j=0;j<8;j++) pk[j] = (n==0) ? (f16)Wlin[kbase+j] : (f16)0.0f;
    }
    *(f16x8*)(Wlds + (size_t)item*8) = pk;
  }
  if (tid < 16) {
    int row = (tid>>2)*1024 + blk*4 + (tid&3);
    prm[tid]      = Wih1[row];
    prm[16 + tid] = bih1[row] + bhh1[row];
    prm[32 + tid] = bih2[row] + bhh2[row];
  }
  if (tid == 16) prm[48] = blin[0];
  __syncthreads();

  // elementwise identity: thread -> (batch row, unit-within-CU)
  const int erow = tid >> 2;
  const int eu   = tid & 3;
  float c1 = 0.f, c2 = 0.f;

  // ---- E1(0): h1(0) from x(0) only ----
  {
    float xv = xg[erow*TS + 0];
    float gi = xv*prm[0*4+eu] + prm[16 + 0*4+eu];
    float gg = xv*prm[2*4+eu] + prm[16 + 2*4+eu];
    float go = xv*prm[3*4+eu] + prm[16 + 3*4+eu];
    c1 = sigm(gi)*tanhf(gg);
    float h1v = sigm(go)*tanhf(c1);
    store_pair_wt(&H1[(size_t)0*BS*HS + erow*HS + blk*4 + eu], eu,
                  __builtin_bit_cast(u16, (f16)h1v));
  }
  bar_arrive(cnt, 0, blk);

  // MFMA identity
  const int wv    = tid >> 6;
  const int lane  = tid & 63;
  const int n15   = lane & 15;
  const int mrow  = wv*16 + n15;          // A-frag row
  const int kc    = (lane>>4)*8;          // A/B-frag k sub-offset
  const int rbase = wv*16 + (lane>>4)*4;  // C/D row base
  const f16x8* WB = (const f16x8*)Wlds;

  for (int t = 0; t < TTS; ++t) {
    bar_wait(cnt, t);   // H1(t), H2(t-1) ready; one L2-inv; loads L2-shared

    const f16* A1  = H1  + (size_t)(t&1)*BS*HS     + mrow*HS + kc;
    const f16* A2h = H2h + (size_t)((t+1)&1)*BS*HS + mrow*HS + kc;  // parity(t-1)
    const f16* A2l = H2l + (size_t)((t+1)&1)*BS*HS + mrow*HS + kc;

    f32x4 acc1  = {0.f,0.f,0.f,0.f};
    f32x4 acc2a = {0.f,0.f,0.f,0.f};
    f32x4 acc2b = {0.f,0.f,0.f,0.f};
    f32x4 accO  = {0.f,0.f,0.f,0.f};
    #pragma unroll 4
    for (int k0 = 0; k0 < KST; ++k0) {
      f16x8 a1  = *(const f16x8*)(A1  + k0*32);
      f16x8 a2h = *(const f16x8*)(A2h + k0*32);
      f16x8 a2l = *(const f16x8*)(A2l + k0*32);
      f16x8 b0 = WB[(0*KST + k0)*64 + lane];
      f16x8 b1 = WB[(1*KST + k0)*64 + lane];
      f16x8 b2 = WB[(2*KST + k0)*64 + lane];
      f16x8 b3 = WB[(3*KST + k0)*64 + lane];
      acc1  = __builtin_amdgcn_mfma_f32_16x16x32_f16(a1,  b0, acc1,  0,0,0);
      acc2a = __builtin_amdgcn_mfma_f32_16x16x32_f16(a1,  b1, acc2a, 0,0,0);
      acc2b = __builtin_amdgcn_mfma_f32_16x16x32_f16(a2h, b2, acc2b, 0,0,0);
      acc2b = __builtin_amdgcn_mfma_f32_16x16x32_f16(a2l, b2, acc2b, 0,0,0);
      accO  = __builtin_amdgcn_mfma_f32_16x16x32_f16(a2h, b3, accO,  0,0,0);
    }
    #pragma unroll
    for (int r = 0; r < 4; ++r) {
      int grow = rbase + r;
      g2s[grow*16 + n15] = acc2a[r] + acc2b[r] + prm[32 + n15];
      g1s[grow*16 + n15] = acc1[r]  + prm[16 + n15];
    }
    if (n15 == 0 && blk == 0 && t >= 1 && t <= TS-1) {
      #pragma unroll
      for (int r = 0; r < 4; ++r) outp[(rbase+r)*TTS + (t-1)] = accO[r] + prm[48];
    }
    __syncthreads();

    // ---- E2(t): c2,h2 update; write-through h2 hi+lo ----
    {
      float gi = g2s[erow*16 + 0*4+eu];
      float gf = g2s[erow*16 + 1*4+eu];
      float gg = g2s[erow*16 + 2*4+eu];
      float go = g2s[erow*16 + 3*4+eu];
      c2 = sigm(gf)*c2 + sigm(gi)*tanhf(gg);
      float h2v = sigm(go)*tanhf(c2);
      f16 hh = (f16)h2v;
      float lo = h2v - (float)hh;
      size_t idx = (size_t)(t&1)*BS*HS + erow*HS + blk*4 + eu;
      store_pair_wt(&H2h[idx], eu, __builtin_bit_cast(u16, hh));
      store_pair_wt(&H2l[idx], eu, __builtin_bit_cast(u16, (f16)lo));
    }

    // ---- AR mini-phase: out(t) = h2(t)·Wlin (hi only), redundant per CU ----
    if (t >= TS-1) {
      bar_arrive(cnt2, t, blk);
      bar_wait(cnt2, t);
      const f16* C2h = H2h + (size_t)(t&1)*BS*HS + mrow*HS + kc;
      f32x4 aco = {0.f,0.f,0.f,0.f};
      #pragma unroll 4
      for (int k0 = 0; k0 < KST; ++k0) {
        f16x8 ah = *(const f16x8*)(C2h + k0*32);
        f16x8 b3 = WB[(3*KST + k0)*64 + lane];
        aco = __builtin_amdgcn_mfma_f32_16x16x32_f16(ah, b3, aco, 0,0,0);
      }
      if (n15 == 0) {
        #pragma unroll
        for (int r = 0; r < 4; ++r) {
          float o = aco[r] + prm[48];
          xfd[rbase + r] = o;
          if (blk == 0) outp[(rbase+r)*TTS + t] = o;
        }
      }
      __syncthreads();
    }

    // ---- E1(t+1): c1,h1 update; write-through h1; arrive cnt[t+1] ----
    if (t < TTS-1) {
      float xv = (t+1 < TS) ? xg[erow*TS + (t+1)] : xfd[erow];
      float gi = g1s[erow*16 + 0*4+eu] + xv*prm[0*4+eu];
      float gf = g1s[erow*16 + 1*4+eu] + xv*prm[1*4+eu];
      float gg = g1s[erow*16 + 2*4+eu] + xv*prm[2*4+eu];
      float go = g1s[erow*16 + 3*4+eu] + xv*prm[3*4+eu];
      c1 = sigm(gf)*c1 + sigm(gi)*tanhf(gg);
      float h1v = sigm(go)*tanhf(c1);
      store_pair_wt(&H1[(size_t)((t+1)&1)*BS*HS + erow*HS + blk*4 + eu], eu,
                    __builtin_bit_cast(u16, (f16)h1v));
      bar_arrive(cnt, t+1, blk);
    }
  }
}

extern "C" void kernel_launch(void* const* d_in, const int* in_sizes, int n_in,
                              void* d_out, int out_size, void* d_ws, size_t ws_size,
                              hipStream_t stream) {
  const float* xg   = (const float*)d_in[0];
  const float* Wih1 = (const float*)d_in[1];
  const float* Whh1 = (const float*)d_in[2];
  const float* bih1 = (const float*)d_in[3];
  const float* bhh1 = (const float*)d_in[4];
  const float* Wih2 = (const float*)d_in[5];
  const float* Whh2 = (const float*)d_in[6];
  const float* bih2 = (const float*)d_in[7];
  const float* bhh2 = (const float*)d_in[8];
  const float* Wlin = (const float*)d_in[9];
  const float* blin = (const float*)d_in[10];
  float* outp = (float*)d_out;
  char* ws = (char*)d_ws;

  init_ws_kernel<<<dim3(128), dim3(256), 0, stream>>>(ws);

  (void)hipFuncSetAttribute((const void*)lstm_coop,
                            hipFuncAttributeMaxDynamicSharedMemorySize, LDS_TOTAL);

  void* args[] = { (void*)&xg, (void*)&Wih1, (void*)&Whh1, (void*)&bih1, (void*)&bhh1,
                   (void*)&Wih2, (void*)&Whh2, (void*)&bih2, (void*)&bhh2,
                   (void*)&Wlin, (void*)&blin, (void*)&outp, (void*)&ws };
  hipError_t err = hipLaunchCooperativeKernel((const void*)lstm_coop,
                                              dim3(NB), dim3(WGS), args, LDS_TOTAL, stream);
  if (err != hipSuccess) {
    lstm_coop<<<dim3(NB), dim3(WGS), LDS_TOTAL, stream>>>(
        xg, Wih1, Whh1, bih1, bhh1, Wih2, Whh2, bih2, bhh2, Wlin, blin, outp, ws);
  }
}

// Round 4
// 8682.053 us; speedup vs baseline: 3.2893x; 1.6669x over previous
//
#include <hip/hip_runtime.h>

// ============================================================================
// 2-layer LSTM (H=1024, B=128, T=256, future=64), persistent cooperative
// kernel, 256 WGs x 512 thr, 1 WG/CU, weights in LDS (MFMA B-frag order).
// R4: XCD-leader coherence with SOUND transport — all flags/counters are
// relaxed agent atomics (coherence-point, mapping-independent, replay-safe).
// Per step: every block arrives (relaxed add); ONE leader per XCC_ID group
// polls arrivals, then does the single fence(acquire,agent) (one L2 inv per
// XCD), then publishes a monotone step flag (atomic). Non-leaders poll the
// flag (relaxed atomic, no fences -> no invalidation storm) and read H with
// plain cached loads served from the freshly-invalidated XCD L2.
// ============================================================================

typedef _Float16 f16;
typedef _Float16 f16x8 __attribute__((ext_vector_type(8)));
typedef float    f32x4 __attribute__((ext_vector_type(4)));
typedef unsigned int   u32;
typedef unsigned short u16;

#define NB   256
#define WGS  512
#define HS   1024
#define BS   128
#define TS   256
#define TTS  320
#define KST  32     // 1024 / 32

// workspace byte offsets
#define OFF_H1    0u         // f16 [2][128][1024]  524288 B
#define OFF_H2H   524288u    // f16 [2][128][1024]
#define OFF_H2L   1048576u   // f16 [2][128][1024]
#define OFF_CNT   1572864u   // int [16 slots x 2048-int stride] = 131072 B
#define OFF_CNT2  1703936u   // int [16 slots x 2048-int stride] = 131072 B
#define OFF_FLAG  1835008u   // int [8 xcd x 2048-int stride]    =  65536 B
#define OFF_XREG  1900544u   // int [8 xcd x 16]                 =    512 B
#define WS_END    1903616u

#define NSLOT       16
#define SLOT_TGT    16       // 256 blocks / 16 slots
#define SLOT_STRIDE 2048     // ints: 8KB between slots

// LDS byte offsets
#define LDS_G1    131072     // float[128][16]
#define LDS_G2    139264     // float[128][16]
#define LDS_XF    147456     // float[128]
#define LDS_PRM   147968     // wih1[16], b1[16], b2[16], blin
#define LDS_MISC  148224     // int[2]: xcd, leader
#define LDS_TOTAL 148480

__device__ __forceinline__ float sigm(float x){ return 1.0f/(1.0f + __expf(-x)); }

__device__ __forceinline__ void wt_store(u32* p, u32 v) {
  __hip_atomic_store(p, v, __ATOMIC_RELAXED, __HIP_MEMORY_SCOPE_AGENT);
}

// pack (even,odd)-unit f16 values; even lanes store 4B write-through
__device__ __forceinline__ void store_pair_wt(f16* addr, int eu, u16 mine) {
  u16 oth = (u16)__shfl_xor((int)mine, 1);
  if ((eu & 1) == 0) {
    u32 pk = (u32)mine | ((u32)oth << 16);
    wt_store((u32*)addr, pk);
  }
}

// arrival: all write-through stores drained, then one relaxed add
__device__ __forceinline__ void bar_arrive(int* cnt, int t, int blk) {
  asm volatile("s_waitcnt vmcnt(0)" ::: "memory");
  __syncthreads();
  if (threadIdx.x == 0)
    __hip_atomic_fetch_add(cnt + (blk & (NSLOT-1)) * SLOT_STRIDE + t, 1,
                           __ATOMIC_RELAXED, __HIP_MEMORY_SCOPE_AGENT);
}

// leader: poll global slots -> ONE fence (L2 inv) -> publish monotone flag.
// non-leader: poll flag with relaxed atomics (no fence).
__device__ __forceinline__ void bar_wait3(const int* cnt, int t, int* flagaddr,
                                          bool leader) {
  if (leader) {
    if (threadIdx.x < NSLOT) {
      const int* p = cnt + threadIdx.x * SLOT_STRIDE + t;
      while (__hip_atomic_load(p, __ATOMIC_RELAXED, __HIP_MEMORY_SCOPE_AGENT) < SLOT_TGT)
        __builtin_amdgcn_s_sleep(1);
    }
    if ((threadIdx.x >> 6) == 0) {
      // wave0 exits poll only when all its poll-lanes are done
      __builtin_amdgcn_fence(__ATOMIC_ACQUIRE, "agent");   // one L1+L2 inv
      asm volatile("s_waitcnt vmcnt(0)" ::: "memory");     // inv complete
    }
    __syncthreads();                                       // release own waves
    if (threadIdx.x == 0)
      __hip_atomic_store(flagaddr, t + 1, __ATOMIC_RELAXED, __HIP_MEMORY_SCOPE_AGENT);
  } else {
    if (threadIdx.x == 0) {
      while (__hip_atomic_load(flagaddr, __ATOMIC_RELAXED, __HIP_MEMORY_SCOPE_AGENT) < t + 1)
        __builtin_amdgcn_s_sleep(1);
    }
    __syncthreads();
  }
}

__global__ void init_ws_kernel(char* ws){
  // zero H2h[1] (786432..1048576) and H2l[1]+cnt+cnt2+flags+xreg (1310720..WS_END)
  const size_t n1 = (1048576u - 786432u) / 16u;
  const size_t n2 = (WS_END   - 1310720u) / 16u;
  float4* r1 = (float4*)(ws + 786432u);
  float4* r2 = (float4*)(ws + 1310720u);
  float4 z = make_float4(0.f, 0.f, 0.f, 0.f);
  size_t stride = (size_t)gridDim.x * blockDim.x;
  for (size_t i = blockIdx.x*(size_t)blockDim.x + threadIdx.x; i < n1; i += stride) r1[i] = z;
  for (size_t i = blockIdx.x*(size_t)blockDim.x + threadIdx.x; i < n2; i += stride) r2[i] = z;
  // push zero-lines to the coherence point so no dirty copies survive in L2s
  __builtin_amdgcn_fence(__ATOMIC_RELEASE, "agent");
}

__global__ void __launch_bounds__(WGS, 2)
lstm_coop(const float* __restrict__ xg,
          const float* __restrict__ Wih1, const float* __restrict__ Whh1,
          const float* __restrict__ bih1, const float* __restrict__ bhh1,
          const float* __restrict__ Wih2, const float* __restrict__ Whh2,
          const float* __restrict__ bih2, const float* __restrict__ bhh2,
          const float* __restrict__ Wlin, const float* __restrict__ blin,
          float* __restrict__ outp, char* __restrict__ ws)
{
  extern __shared__ char smem[];
  f16*   Wlds = (f16*)smem;                    // [(tile*32+k0)*64+lane]*8 f16
  float* g1s  = (float*)(smem + LDS_G1);
  float* g2s  = (float*)(smem + LDS_G2);
  float* xfd  = (float*)(smem + LDS_XF);
  float* prm  = (float*)(smem + LDS_PRM);
  int*   miscl= (int*)(smem + LDS_MISC);

  f16* H1  = (f16*)(ws + OFF_H1);
  f16* H2h = (f16*)(ws + OFF_H2H);
  f16* H2l = (f16*)(ws + OFF_H2L);
  int* cnt  = (int*)(ws + OFF_CNT);
  int* cnt2 = (int*)(ws + OFF_CNT2);
  int* flags= (int*)(ws + OFF_FLAG);

  const int tid = threadIdx.x;
  const int blk = blockIdx.x;

  // ---- XCD self-identification + leader election (self-consistent even if
  // XCC_ID were misread: every group has exactly one rank-0 leader) ----
  int xcd_raw;
  asm("s_getreg_b32 %0, hwreg(HW_REG_XCC_ID)" : "=s"(xcd_raw));
  if (tid == 0) {
    int x = xcd_raw & 7;
    int rank = __hip_atomic_fetch_add((int*)(ws + OFF_XREG) + x*16, 1,
                                      __ATOMIC_RELAXED, __HIP_MEMORY_SCOPE_AGENT);
    miscl[0] = x;
    miscl[1] = (rank == 0) ? 1 : 0;
  }

  // ---- prologue: pack weights into LDS in MFMA B-fragment order ----
  // tiles: 0=G1(Whh1) 1=G2a(Wih2) 2=G2b(Whh2) 3=OUT(Wlin col0, rest 0)
  for (int item = tid; item < 4*KST*64; item += WGS) {
    int tile = item >> 11;
    int rem  = item & 2047;
    int k0   = rem >> 6;
    int lane = rem & 63;
    int n    = lane & 15;
    int kbase = k0*32 + (lane>>4)*8;
    f16x8 pk;
    if (tile < 3) {
      const float* Wsrc = (tile==0) ? Whh1 : (tile==1) ? Wih2 : Whh2;
      const float* p = Wsrc + (size_t)((n>>2)*1024 + blk*4 + (n&3))*HS + kbase;
      #pragma unroll
      for (int j=0;j<8;j++) pk[j] = (f16)p[j];
    } else {
      #pragma unroll
      for (int j=0;j<8;j++) pk[j] = (n==0) ? (f16)Wlin[kbase+j] : (f16)0.0f;
    }
    *(f16x8*)(Wlds + (size_t)item*8) = pk;
  }
  if (tid < 16) {
    int row = (tid>>2)*1024 + blk*4 + (tid&3);
    prm[tid]      = Wih1[row];
    prm[16 + tid] = bih1[row] + bhh1[row];
    prm[32 + tid] = bih2[row] + bhh2[row];
  }
  if (tid == 16) prm[48] = blin[0];
  __syncthreads();

  const int  myxcd  = miscl[0];
  const bool leader = miscl[1] != 0;
  int* flag_main = flags + myxcd * SLOT_STRIDE;        // monotone t+1
  int* flag_ar   = flags + myxcd * SLOT_STRIDE + 64;   // monotone t+1 (AR)

  // elementwise identity: thread -> (batch row, unit-within-CU)
  const int erow = tid >> 2;
  const int eu   = tid & 3;
  float c1 = 0.f, c2 = 0.f;

  // ---- E1(0): h1(0) from x(0) only ----
  {
    float xv = xg[erow*TS + 0];
    float gi = xv*prm[0*4+eu] + prm[16 + 0*4+eu];
    float gg = xv*prm[2*4+eu] + prm[16 + 2*4+eu];
    float go = xv*prm[3*4+eu] + prm[16 + 3*4+eu];
    c1 = sigm(gi)*tanhf(gg);
    float h1v = sigm(go)*tanhf(c1);
    store_pair_wt(&H1[(size_t)0*BS*HS + erow*HS + blk*4 + eu], eu,
                  __builtin_bit_cast(u16, (f16)h1v));
  }
  bar_arrive(cnt, 0, blk);

  // MFMA identity
  const int wv    = tid >> 6;
  const int lane  = tid & 63;
  const int n15   = lane & 15;
  const int mrow  = wv*16 + n15;          // A-frag row
  const int kc    = (lane>>4)*8;          // A/B-frag k sub-offset
  const int rbase = wv*16 + (lane>>4)*4;  // C/D row base
  const f16x8* WB = (const f16x8*)Wlds;

  for (int t = 0; t < TTS; ++t) {
    bar_wait3(cnt, t, flag_main, leader);  // H1(t), H2(t-1) ready; L2 fresh

    // hoist next-step x load (plain cached; x is read-only)
    float xv_next = 0.0f;
    if (t+1 < TS) xv_next = xg[erow*TS + (t+1)];

    const f16* A1  = H1  + (size_t)(t&1)*BS*HS     + mrow*HS + kc;
    const f16* A2h = H2h + (size_t)((t+1)&1)*BS*HS + mrow*HS + kc;  // parity(t-1)
    const f16* A2l = H2l + (size_t)((t+1)&1)*BS*HS + mrow*HS + kc;

    f32x4 acc1  = {0.f,0.f,0.f,0.f};
    f32x4 acc2a = {0.f,0.f,0.f,0.f};
    f32x4 acc2b = {0.f,0.f,0.f,0.f};
    f32x4 accO  = {0.f,0.f,0.f,0.f};
    #pragma unroll 8
    for (int k0 = 0; k0 < KST; ++k0) {
      f16x8 a1  = *(const f16x8*)(A1  + k0*32);
      f16x8 a2h = *(const f16x8*)(A2h + k0*32);
      f16x8 a2l = *(const f16x8*)(A2l + k0*32);
      f16x8 b0 = WB[(0*KST + k0)*64 + lane];
      f16x8 b1 = WB[(1*KST + k0)*64 + lane];
      f16x8 b2 = WB[(2*KST + k0)*64 + lane];
      f16x8 b3 = WB[(3*KST + k0)*64 + lane];
      acc1  = __builtin_amdgcn_mfma_f32_16x16x32_f16(a1,  b0, acc1,  0,0,0);
      acc2a = __builtin_amdgcn_mfma_f32_16x16x32_f16(a1,  b1, acc2a, 0,0,0);
      acc2b = __builtin_amdgcn_mfma_f32_16x16x32_f16(a2h, b2, acc2b, 0,0,0);
      acc2b = __builtin_amdgcn_mfma_f32_16x16x32_f16(a2l, b2, acc2b, 0,0,0);
      accO  = __builtin_amdgcn_mfma_f32_16x16x32_f16(a2h, b3, accO,  0,0,0);
    }
    #pragma unroll
    for (int r = 0; r < 4; ++r) {
      int grow = rbase + r;
      g2s[grow*16 + n15] = acc2a[r] + acc2b[r] + prm[32 + n15];
      g1s[grow*16 + n15] = acc1[r]  + prm[16 + n15];
    }
    if (n15 == 0 && blk == 0 && t >= 1 && t <= TS-1) {
      #pragma unroll
      for (int r = 0; r < 4; ++r)
        wt_store((u32*)&outp[(rbase+r)*TTS + (t-1)],
                 __builtin_bit_cast(u32, accO[r] + prm[48]));
    }
    __syncthreads();

    // ---- E2(t): c2,h2 update; write-through h2 hi+lo ----
    {
      float gi = g2s[erow*16 + 0*4+eu];
      float gf = g2s[erow*16 + 1*4+eu];
      float gg = g2s[erow*16 + 2*4+eu];
      float go = g2s[erow*16 + 3*4+eu];
      c2 = sigm(gf)*c2 + sigm(gi)*tanhf(gg);
      float h2v = sigm(go)*tanhf(c2);
      f16 hh = (f16)h2v;
      float lo = h2v - (float)hh;
      size_t idx = (size_t)(t&1)*BS*HS + erow*HS + blk*4 + eu;
      store_pair_wt(&H2h[idx], eu, __builtin_bit_cast(u16, hh));
      store_pair_wt(&H2l[idx], eu, __builtin_bit_cast(u16, (f16)lo));
    }

    // ---- AR mini-phase: out(t) = h2(t)·Wlin (hi only), redundant per CU ----
    if (t >= TS-1) {
      bar_arrive(cnt2, t, blk);
      bar_wait3(cnt2, t, flag_ar, leader);
      const f16* C2h = H2h + (size_t)(t&1)*BS*HS + mrow*HS + kc;
      f32x4 aco = {0.f,0.f,0.f,0.f};
      #pragma unroll 8
      for (int k0 = 0; k0 < KST; ++k0) {
        f16x8 ah = *(const f16x8*)(C2h + k0*32);
        f16x8 b3 = WB[(3*KST + k0)*64 + lane];
        aco = __builtin_amdgcn_mfma_f32_16x16x32_f16(ah, b3, aco, 0,0,0);
      }
      if (n15 == 0) {
        #pragma unroll
        for (int r = 0; r < 4; ++r) {
          float o = aco[r] + prm[48];
          xfd[rbase + r] = o;
          if (blk == 0)
            wt_store((u32*)&outp[(rbase+r)*TTS + t], __builtin_bit_cast(u32, o));
        }
      }
      __syncthreads();
    }

    // ---- E1(t+1): c1,h1 update; write-through h1; arrive cnt[t+1] ----
    if (t < TTS-1) {
      float xv = (t+1 < TS) ? xv_next : xfd[erow];
      float gi = g1s[erow*16 + 0*4+eu] + xv*prm[0*4+eu];
      float gf = g1s[erow*16 + 1*4+eu] + xv*prm[1*4+eu];
      float gg = g1s[erow*16 + 2*4+eu] + xv*prm[2*4+eu];
      float go = g1s[erow*16 + 3*4+eu] + xv*prm[3*4+eu];
      c1 = sigm(gf)*c1 + sigm(gi)*tanhf(gg);
      float h1v = sigm(go)*tanhf(c1);
      store_pair_wt(&H1[(size_t)((t+1)&1)*BS*HS + erow*HS + blk*4 + eu], eu,
                    __builtin_bit_cast(u16, (f16)h1v));
      bar_arrive(cnt, t+1, blk);
    }
  }
}

extern "C" void kernel_launch(void* const* d_in, const int* in_sizes, int n_in,
                              void* d_out, int out_size, void* d_ws, size_t ws_size,
                              hipStream_t stream) {
  const float* xg   = (const float*)d_in[0];
  const float* Wih1 = (const float*)d_in[1];
  const float* Whh1 = (const float*)d_in[2];
  const float* bih1 = (const float*)d_in[3];
  const float* bhh1 = (const float*)d_in[4];
  const float* Wih2 = (const float*)d_in[5];
  const float* Whh2 = (const float*)d_in[6];
  const float* bih2 = (const float*)d_in[7];
  const float* bhh2 = (const float*)d_in[8];
  const float* Wlin = (const float*)d_in[9];
  const float* blin = (const float*)d_in[10];
  float* outp = (float*)d_out;
  char* ws = (char*)d_ws;

  init_ws_kernel<<<dim3(128), dim3(256), 0, stream>>>(ws);

  (void)hipFuncSetAttribute((const void*)lstm_coop,
                            hipFuncAttributeMaxDynamicSharedMemorySize, LDS_TOTAL);

  void* args[] = { (void*)&xg, (void*)&Wih1, (void*)&Whh1, (void*)&bih1, (void*)&bhh1,
                   (void*)&Wih2, (void*)&Whh2, (void*)&bih2, (void*)&bhh2,
                   (void*)&Wlin, (void*)&blin, (void*)&outp, (void*)&ws };
  hipError_t err = hipLaunchCooperativeKernel((const void*)lstm_coop,
                                              dim3(NB), dim3(WGS), args, LDS_TOTAL, stream);
  if (err != hipSuccess) {
    lstm_coop<<<dim3(NB), dim3(WGS), LDS_TOTAL, stream>>>(
        xg, Wih1, Whh1, bih1, bhh1, Wih2, Whh2, bih2, bhh2, Wlin, blin, outp, ws);
  }
}

// Round 5
// 5279.483 us; speedup vs baseline: 5.4092x; 1.6445x over previous
//
#include <hip/hip_runtime.h>

// ============================================================================
// 2-layer LSTM (H=1024, B=128, T=256, future=64), persistent cooperative
// kernel, 256 WGs x 512 thr, 1 WG/CU, weights in LDS (MFMA B-frag order).
// R5: HBM-RMW fix — H buffers re-laid out as [hblk=256][batch=128][4units]
// so each CU writes ONE contiguous 1KB chunk per buffer per step (LDS-staged,
// full-line global_store_dwordx4 sc0 sc1: no cross-XCD false sharing, no
// partial-line RMW). Readers rebuild A-fragments from two 8B loads. AR-step
// output = per-CU partial dot (h2 in regs) + f32 atomic-add reduction at the
// coherence point (no 256KB redundant re-read, fence-free consumer path).
// Barrier: R4's XCD-leader scheme (one L2-inv per XCD per step).
// ============================================================================

typedef _Float16 f16;
typedef _Float16 f16x8 __attribute__((ext_vector_type(8)));
typedef _Float16 f16x4 __attribute__((ext_vector_type(4)));
typedef float    f32x4 __attribute__((ext_vector_type(4)));
typedef int      i32x4 __attribute__((ext_vector_type(4)));
typedef unsigned int   u32;
typedef unsigned short u16;

#define NB   256
#define WGS  512
#define HS   1024
#define BS   128
#define TS   256
#define TTS  320
#define KST  32     // 1024 / 32
#define PSTR 131072 // f16 elems per parity plane: 256*128*4

// workspace byte offsets
#define OFF_H1    0u         // f16 [2][256][128][4]  524288 B
#define OFF_H2H   524288u    // f16 [2][256][128][4]
#define OFF_H2L   1048576u   // f16 [2][256][128][4]
#define OFF_CNT   1572864u   // int [32 slots x 2048-int stride] = 262144 B
#define OFF_CNT2  1835008u   // int [32 slots x 2048-int stride] = 262144 B
#define OFF_FLAG  2097152u   // int [8 xcd x 2048-int stride]    =  65536 B
#define OFF_XREG  2162688u   // int [8 xcd x 16]                 =    512 B
#define OFF_ACC   2163200u   // float [65][128]                  =  33280 B
#define WS_END    2196480u

#define NSLOT       32
#define SLOT_TGT    8        // 256 blocks / 32 slots
#define SLOT_STRIDE 2048     // ints: 8KB between slots

// LDS byte offsets
#define LDS_G1    131072     // float[128][16]
#define LDS_G2    139264     // float[128][16]
#define LDS_XF    147456     // float[128]
#define LDS_PRM   147968     // wih1[16], b1[16], b2[16], blin
#define LDS_MISC  148224     // int[2]: xcd, leader
#define LDS_SH1   148352     // f16[512] stage h1
#define LDS_SH2H  149376     // f16[512] stage h2 hi
#define LDS_SH2L  150400     // f16[512] stage h2 lo
#define LDS_TOTAL 151552

__device__ __forceinline__ float sigm(float x){ return 1.0f/(1.0f + __expf(-x)); }

__device__ __forceinline__ void wt_store(u32* p, u32 v) {
  __hip_atomic_store(p, v, __ATOMIC_RELAXED, __HIP_MEMORY_SCOPE_AGENT);
}

// full-line write-through 16B store (to coherence point, MALL-allocating)
__device__ __forceinline__ void st16_wt(f16* addr, f16x8 v) {
  i32x4 d = __builtin_bit_cast(i32x4, v);
  asm volatile("global_store_dwordx4 %0, %1, off sc0 sc1"
               :: "v"(addr), "v"(d) : "memory");
}

// arrival: all pending stores/atomics drained, then one relaxed add
__device__ __forceinline__ void bar_arrive(int* cnt, int t, int blk) {
  asm volatile("s_waitcnt vmcnt(0)" ::: "memory");
  __syncthreads();
  if (threadIdx.x == 0)
    __hip_atomic_fetch_add(cnt + (blk & (NSLOT-1)) * SLOT_STRIDE + t, 1,
                           __ATOMIC_RELAXED, __HIP_MEMORY_SCOPE_AGENT);
}

// leader: poll global slots -> ONE fence (L2 inv) -> publish monotone flag.
// non-leader: poll flag with relaxed atomics (no fence).
__device__ __forceinline__ void bar_wait3(const int* cnt, int t, int* flagaddr,
                                          bool leader) {
  if (leader) {
    if (threadIdx.x < NSLOT) {
      const int* p = cnt + threadIdx.x * SLOT_STRIDE + t;
      while (__hip_atomic_load(p, __ATOMIC_RELAXED, __HIP_MEMORY_SCOPE_AGENT) < SLOT_TGT)
        __builtin_amdgcn_s_sleep(1);
    }
    if ((threadIdx.x >> 6) == 0) {
      __builtin_amdgcn_fence(__ATOMIC_ACQUIRE, "agent");   // one L1+L2 inv
      asm volatile("s_waitcnt vmcnt(0)" ::: "memory");
    }
    __syncthreads();
    if (threadIdx.x == 0)
      __hip_atomic_store(flagaddr, t + 1, __ATOMIC_RELAXED, __HIP_MEMORY_SCOPE_AGENT);
  } else {
    if (threadIdx.x == 0) {
      while (__hip_atomic_load(flagaddr, __ATOMIC_RELAXED, __HIP_MEMORY_SCOPE_AGENT) < t + 1)
        __builtin_amdgcn_s_sleep(1);
    }
    __syncthreads();
  }
}

__global__ void init_ws_kernel(char* ws){
  // zero H2h[1] (786432..1048576) and H2l[1]+cnt+cnt2+flags+xreg+acc
  const size_t n1 = (1048576u - 786432u) / 16u;
  const size_t n2 = (WS_END   - 1310720u) / 16u;
  float4* r1 = (float4*)(ws + 786432u);
  float4* r2 = (float4*)(ws + 1310720u);
  float4 z = make_float4(0.f, 0.f, 0.f, 0.f);
  size_t stride = (size_t)gridDim.x * blockDim.x;
  for (size_t i = blockIdx.x*(size_t)blockDim.x + threadIdx.x; i < n1; i += stride) r1[i] = z;
  for (size_t i = blockIdx.x*(size_t)blockDim.x + threadIdx.x; i < n2; i += stride) r2[i] = z;
  __builtin_amdgcn_fence(__ATOMIC_RELEASE, "agent");
}

__global__ void __launch_bounds__(WGS, 2)
lstm_coop(const float* __restrict__ xg,
          const float* __restrict__ Wih1, const float* __restrict__ Whh1,
          const float* __restrict__ bih1, const float* __restrict__ bhh1,
          const float* __restrict__ Wih2, const float* __restrict__ Whh2,
          const float* __restrict__ bih2, const float* __restrict__ bhh2,
          const float* __restrict__ Wlin, const float* __restrict__ blin,
          float* __restrict__ outp, char* __restrict__ ws)
{
  extern __shared__ char smem[];
  f16*   Wlds = (f16*)smem;                    // [(tile*32+k0)*64+lane]*8 f16
  float* g1s  = (float*)(smem + LDS_G1);
  float* g2s  = (float*)(smem + LDS_G2);
  float* xfd  = (float*)(smem + LDS_XF);
  float* prm  = (float*)(smem + LDS_PRM);
  int*   miscl= (int*)(smem + LDS_MISC);
  f16*   sh1  = (f16*)(smem + LDS_SH1);
  f16*   sh2h = (f16*)(smem + LDS_SH2H);
  f16*   sh2l = (f16*)(smem + LDS_SH2L);

  f16* H1  = (f16*)(ws + OFF_H1);
  f16* H2h = (f16*)(ws + OFF_H2H);
  f16* H2l = (f16*)(ws + OFF_H2L);
  int* cnt  = (int*)(ws + OFF_CNT);
  int* cnt2 = (int*)(ws + OFF_CNT2);
  int* flags= (int*)(ws + OFF_FLAG);
  float* accs = (float*)(ws + OFF_ACC);

  const int tid = threadIdx.x;
  const int blk = blockIdx.x;

  // ---- XCD self-identification + leader election ----
  int xcd_raw;
  asm("s_getreg_b32 %0, hwreg(HW_REG_XCC_ID)" : "=s"(xcd_raw));
  if (tid == 0) {
    int x = xcd_raw & 7;
    int rank = __hip_atomic_fetch_add((int*)(ws + OFF_XREG) + x*16, 1,
                                      __ATOMIC_RELAXED, __HIP_MEMORY_SCOPE_AGENT);
    miscl[0] = x;
    miscl[1] = (rank == 0) ? 1 : 0;
  }

  // ---- prologue: pack weights into LDS in MFMA B-fragment order ----
  // tiles: 0=G1(Whh1) 1=G2a(Wih2) 2=G2b(Whh2) 3=OUT(Wlin col0, rest 0)
  for (int item = tid; item < 4*KST*64; item += WGS) {
    int tile = item >> 11;
    int rem  = item & 2047;
    int k0   = rem >> 6;
    int lane = rem & 63;
    int n    = lane & 15;
    int kbase = k0*32 + (lane>>4)*8;
    f16x8 pk;
    if (tile < 3) {
      const float* Wsrc = (tile==0) ? Whh1 : (tile==1) ? Wih2 : Whh2;
      const float* p = Wsrc + (size_t)((n>>2)*1024 + blk*4 + (n&3))*HS + kbase;
      #pragma unroll
      for (int j=0;j<8;j++) pk[j] = (f16)p[j];
    } else {
      #pragma unroll
      for (int j=0;j<8;j++) pk[j] = (n==0) ? (f16)Wlin[kbase+j] : (f16)0.0f;
    }
    *(f16x8*)(Wlds + (size_t)item*8) = pk;
  }
  if (tid < 16) {
    int row = (tid>>2)*1024 + blk*4 + (tid&3);
    prm[tid]      = Wih1[row];
    prm[16 + tid] = bih1[row] + bhh1[row];
    prm[32 + tid] = bih2[row] + bhh2[row];
  }
  if (tid == 16) prm[48] = blin[0];

  // elementwise identity: thread -> (batch row, unit-within-CU)
  const int erow = tid >> 2;
  const int eu   = tid & 3;
  const float wlin_c = Wlin[blk*4 + eu];  // for AR partial dot
  float c1 = 0.f, c2 = 0.f;
  __syncthreads();

  const int  myxcd  = miscl[0];
  const bool leader = miscl[1] != 0;
  int* flag_main = flags + myxcd * SLOT_STRIDE;        // monotone t+1

  // co-op store identity: wave wv stores buffer chunk (lane-l 16B slices)
  const int wv    = tid >> 6;
  const int lane  = tid & 63;

  // ---- E1(0): h1(0) from x(0) only; stage + co-op store (parity 0) ----
  {
    float xv = xg[erow*TS + 0];
    float gi = xv*prm[0*4+eu] + prm[16 + 0*4+eu];
    float gg = xv*prm[2*4+eu] + prm[16 + 2*4+eu];
    float go = xv*prm[3*4+eu] + prm[16 + 3*4+eu];
    c1 = sigm(gi)*tanhf(gg);
    float h1v = sigm(go)*tanhf(c1);
    sh1[tid] = (f16)h1v;
  }
  __syncthreads();
  if (wv == 0)
    st16_wt(H1 + (size_t)blk*512 + lane*8, *(const f16x8*)(sh1 + lane*8));
  bar_arrive(cnt, 0, blk);

  // MFMA identity
  const int n15   = lane & 15;
  const int mrow  = wv*16 + n15;          // A-frag row (batch)
  const int kc    = (lane>>4)*8;          // A/B-frag k sub-offset
  const int rbase = wv*16 + (lane>>4)*4;  // C/D row base
  const f16x8* WB = (const f16x8*)Wlds;
  // A-frag base offset in new layout: elem(batch,k) at (k>>2)*512 + batch*4 + (k&3)
  const int abase = mrow*4 + (kc>>2)*512;

  for (int t = 0; t < TTS; ++t) {
    bar_wait3(cnt, t, flag_main, leader);  // H1(t), H2(t-1) visible; L2 fresh

    float xv_next = 0.0f;
    if (t+1 < TS) xv_next = xg[erow*TS + (t+1)];

    const f16* A1  = H1  + (size_t)(t&1)*PSTR     + abase;
    const f16* A2h = H2h + (size_t)((t+1)&1)*PSTR + abase;  // parity(t-1)
    const f16* A2l = H2l + (size_t)((t+1)&1)*PSTR + abase;

    f32x4 acc1  = {0.f,0.f,0.f,0.f};
    f32x4 acc2a = {0.f,0.f,0.f,0.f};
    f32x4 acc2b = {0.f,0.f,0.f,0.f};
    f32x4 accO  = {0.f,0.f,0.f,0.f};
    #pragma unroll 8
    for (int k0 = 0; k0 < KST; ++k0) {
      f16x4 a1l  = *(const f16x4*)(A1  + k0*4096);
      f16x4 a1h  = *(const f16x4*)(A1  + k0*4096 + 512);
      f16x4 a2hl = *(const f16x4*)(A2h + k0*4096);
      f16x4 a2hh = *(const f16x4*)(A2h + k0*4096 + 512);
      f16x4 a2ll = *(const f16x4*)(A2l + k0*4096);
      f16x4 a2lh = *(const f16x4*)(A2l + k0*4096 + 512);
      f16x8 a1  = __builtin_shufflevector(a1l,  a1h,  0,1,2,3,4,5,6,7);
      f16x8 a2h = __builtin_shufflevector(a2hl, a2hh, 0,1,2,3,4,5,6,7);
      f16x8 a2l = __builtin_shufflevector(a2ll, a2lh, 0,1,2,3,4,5,6,7);
      f16x8 b0 = WB[(0*KST + k0)*64 + lane];
      f16x8 b1 = WB[(1*KST + k0)*64 + lane];
      f16x8 b2 = WB[(2*KST + k0)*64 + lane];
      f16x8 b3 = WB[(3*KST + k0)*64 + lane];
      acc1  = __builtin_amdgcn_mfma_f32_16x16x32_f16(a1,  b0, acc1,  0,0,0);
      acc2a = __builtin_amdgcn_mfma_f32_16x16x32_f16(a1,  b1, acc2a, 0,0,0);
      acc2b = __builtin_amdgcn_mfma_f32_16x16x32_f16(a2h, b2, acc2b, 0,0,0);
      acc2b = __builtin_amdgcn_mfma_f32_16x16x32_f16(a2l, b2, acc2b, 0,0,0);
      accO  = __builtin_amdgcn_mfma_f32_16x16x32_f16(a2h, b3, accO,  0,0,0);
    }
    #pragma unroll
    for (int r = 0; r < 4; ++r) {
      int grow = rbase + r;
      g2s[grow*16 + n15] = acc2a[r] + acc2b[r] + prm[32 + n15];
      g1s[grow*16 + n15] = acc1[r]  + prm[16 + n15];
    }
    if (n15 == 0 && blk == 0 && t >= 1 && t <= TS-1) {
      #pragma unroll
      for (int r = 0; r < 4; ++r)
        wt_store((u32*)&outp[(rbase+r)*TTS + (t-1)],
                 __builtin_bit_cast(u32, accO[r] + prm[48]));
    }
    __syncthreads();

    // ---- E2(t): c2,h2 update; stage hi/lo to LDS ----
    float h2v;
    {
      float gi = g2s[erow*16 + 0*4+eu];
      float gf = g2s[erow*16 + 1*4+eu];
      float gg = g2s[erow*16 + 2*4+eu];
      float go = g2s[erow*16 + 3*4+eu];
      c2 = sigm(gf)*c2 + sigm(gi)*tanhf(gg);
      h2v = sigm(go)*tanhf(c2);
      f16 hh = (f16)h2v;
      sh2h[tid] = hh;
      sh2l[tid] = (f16)(h2v - (float)hh);
    }

    // ---- AR phase: out(t) = h2(t)·Wlin + blin via atomic-add reduction ----
    if (t >= TS-1) {
      int aidx = t - (TS-1);
      float p = h2v * wlin_c;
      p += __shfl_xor(p, 1);
      p += __shfl_xor(p, 2);
      if (eu == 0)
        __hip_atomic_fetch_add(accs + aidx*BS + erow, p,
                               __ATOMIC_RELAXED, __HIP_MEMORY_SCOPE_AGENT);
      bar_arrive(cnt2, t, blk);
      if (tid < NSLOT) {   // fence-free poll: slots are per-t (never reused)
        const int* pp = cnt2 + tid * SLOT_STRIDE + t;
        while (__hip_atomic_load(pp, __ATOMIC_RELAXED, __HIP_MEMORY_SCOPE_AGENT) < SLOT_TGT)
          __builtin_amdgcn_s_sleep(1);
      }
      __syncthreads();
      if (tid < BS)        // atomic loads bypass caches -> fresh sums
        xfd[tid] = __hip_atomic_load(accs + aidx*BS + tid,
                                     __ATOMIC_RELAXED, __HIP_MEMORY_SCOPE_AGENT) + prm[48];
      __syncthreads();
      if (blk == 0 && tid < BS)
        wt_store((u32*)&outp[tid*TTS + t], __builtin_bit_cast(u32, xfd[tid]));
    }

    // ---- E1(t+1): c1,h1 update; stage ----
    if (t < TTS-1) {
      float xv = (t+1 < TS) ? xv_next : xfd[erow];
      float gi = g1s[erow*16 + 0*4+eu] + xv*prm[0*4+eu];
      float gf = g1s[erow*16 + 1*4+eu] + xv*prm[1*4+eu];
      float gg = g1s[erow*16 + 2*4+eu] + xv*prm[2*4+eu];
      float go = g1s[erow*16 + 3*4+eu] + xv*prm[3*4+eu];
      c1 = sigm(gf)*c1 + sigm(gi)*tanhf(gg);
      float h1v = sigm(go)*tanhf(c1);
      sh1[tid] = (f16)h1v;
    }
    __syncthreads();   // stages complete

    // ---- co-op full-line stores: 1KB contiguous chunk per buffer ----
    if (wv == 0 && t < TTS-1)   // h1(t+1), parity (t+1)&1
      st16_wt(H1 + (size_t)((t+1)&1)*PSTR + blk*512 + lane*8,
              *(const f16x8*)(sh1 + lane*8));
    else if (wv == 1)           // h2 hi (t), parity t&1
      st16_wt(H2h + (size_t)(t&1)*PSTR + blk*512 + lane*8,
              *(const f16x8*)(sh2h + lane*8));
    else if (wv == 2)           // h2 lo (t), parity t&1
      st16_wt(H2l + (size_t)(t&1)*PSTR + blk*512 + lane*8,
              *(const f16x8*)(sh2l + lane*8));

    if (t < TTS-1) bar_arrive(cnt, t+1, blk);
  }
}

extern "C" void kernel_launch(void* const* d_in, const int* in_sizes, int n_in,
                              void* d_out, int out_size, void* d_ws, size_t ws_size,
                              hipStream_t stream) {
  const float* xg   = (const float*)d_in[0];
  const float* Wih1 = (const float*)d_in[1];
  const float* Whh1 = (const float*)d_in[2];
  const float* bih1 = (const float*)d_in[3];
  const float* bhh1 = (const float*)d_in[4];
  const float* Wih2 = (const float*)d_in[5];
  const float* Whh2 = (const float*)d_in[6];
  const float* bih2 = (const float*)d_in[7];
  const float* bhh2 = (const float*)d_in[8];
  const float* Wlin = (const float*)d_in[9];
  const float* blin = (const float*)d_in[10];
  float* outp = (float*)d_out;
  char* ws = (char*)d_ws;

  init_ws_kernel<<<dim3(128), dim3(256), 0, stream>>>(ws);

  (void)hipFuncSetAttribute((const void*)lstm_coop,
                            hipFuncAttributeMaxDynamicSharedMemorySize, LDS_TOTAL);

  void* args[] = { (void*)&xg, (void*)&Wih1, (void*)&Whh1, (void*)&bih1, (void*)&bhh1,
                   (void*)&Wih2, (void*)&Whh2, (void*)&bih2, (void*)&bhh2,
                   (void*)&Wlin, (void*)&blin, (void*)&outp, (void*)&ws };
  hipError_t err = hipLaunchCooperativeKernel((const void*)lstm_coop,
                                              dim3(NB), dim3(WGS), args, LDS_TOTAL, stream);
  if (err != hipSuccess) {
    lstm_coop<<<dim3(NB), dim3(WGS), LDS_TOTAL, stream>>>(
        xg, Wih1, Whh1, bih1, bhh1, Wih2, Whh2, bih2, bhh2, Wlin, blin, outp, ws);
  }
}